// Round 1
// baseline (641.417 us; speedup 1.0000x reference)
//
#include <hip/hip_runtime.h>
#include <hip/hip_bf16.h>
#include <math.h>

#define N_NODES 100000
#define N_EDGES 1600000
#define F 64          // IN_FEATS == HIDDEN == 64
#define NCLS 2

// ---------------------------------------------------------------------------
// Kernel 1: h = feat @ W_in + b_in ; a[n] = h[n]·W_u ; b[n] = h[n]·W_v
// One 64-lane wave per node, 4 nodes per 256-thread block.
// W_in staged in LDS (16 KB). f_k broadcast via __shfl across the wave.
// ---------------------------------------------------------------------------
__global__ __launch_bounds__(256) void node_mlp_kernel(
    const float* __restrict__ feat,
    const float* __restrict__ W_in,   // (64,64) row-major: W_in[k*64+j]
    const float* __restrict__ b_in,   // (64,)
    const float* __restrict__ W_edge, // (128,1): [0:64]=W_u, [64:128]=W_v
    float* __restrict__ h,            // (N,64)
    float* __restrict__ A,            // (N,) per-node src-gate scalar
    float* __restrict__ B)            // (N,) per-node dst-gate scalar
{
    __shared__ float sW[F * F];
    __shared__ float sWu[F];
    __shared__ float sWv[F];
    __shared__ float sb[F];

    for (int i = threadIdx.x; i < F * F; i += 256) sW[i] = W_in[i];
    if (threadIdx.x < F) {
        sWu[threadIdx.x] = W_edge[threadIdx.x];
        sWv[threadIdx.x] = W_edge[F + threadIdx.x];
        sb[threadIdx.x]  = b_in[threadIdx.x];
    }
    __syncthreads();

    const int lane = threadIdx.x & 63;
    const int wid  = threadIdx.x >> 6;
    const int n    = blockIdx.x * 4 + wid;
    if (n >= N_NODES) return;

    const float f = feat[n * F + lane];   // lane j holds feat[n][j]
    float acc = sb[lane];
    #pragma unroll
    for (int k = 0; k < F; ++k) {
        acc += __shfl(f, k) * sW[k * F + lane];
    }

    // per-node gate scalars: reduce acc*Wu, acc*Wv across the wave
    float au = acc * sWu[lane];
    float av = acc * sWv[lane];
    #pragma unroll
    for (int off = 32; off > 0; off >>= 1) {
        au += __shfl_xor(au, off);
        av += __shfl_xor(av, off);
    }

    h[n * F + lane] = acc;
    if (lane == 0) { A[n] = au; B[n] = av; }
}

// ---------------------------------------------------------------------------
// Kernel 2: per-edge gather + gated scatter-add.
// One wave per edge (grid-stride over edges). Lane j handles feature j:
// coalesced 256 B gather of h[src], coalesced atomicAdd into agg[dst].
// ---------------------------------------------------------------------------
__global__ __launch_bounds__(256) void edge_scatter_kernel(
    const int* __restrict__ src,
    const int* __restrict__ dst,
    const float* __restrict__ h,
    const float* __restrict__ A,
    const float* __restrict__ B,
    const float* __restrict__ b_edge,  // scalar
    float* __restrict__ agg,           // (N,64), pre-zeroed
    float* __restrict__ deg)           // (N,),  pre-zeroed
{
    const int lane   = threadIdx.x & 63;
    const int wave   = (blockIdx.x * blockDim.x + threadIdx.x) >> 6;
    const int nwaves = (gridDim.x * blockDim.x) >> 6;
    const float be = b_edge[0];

    for (int e = wave; e < N_EDGES; e += nwaves) {
        const int s = src[e];
        const int d = dst[e];
        const float x = A[s] + B[d] + be;          // scalar loads: wave-broadcast
        const float w = 1.0f / (1.0f + expf(-x));  // sigmoid
        const float msg = h[s * F + lane] * w;
        atomicAdd(&agg[d * F + lane], msg);
        if (lane == 0) atomicAdd(&deg[d], 1.0f);
    }
}

// ---------------------------------------------------------------------------
// Kernel 3: h_new = deg>0 ? agg : h ;  out = h_new @ W_out + b_out
// One wave per node; butterfly reduce the two class dots.
// ---------------------------------------------------------------------------
__global__ __launch_bounds__(256) void out_kernel(
    const float* __restrict__ h,
    const float* __restrict__ agg,
    const float* __restrict__ deg,
    const float* __restrict__ W_out,  // (64,2) row-major
    const float* __restrict__ b_out,  // (2,)
    float* __restrict__ out)          // (N,2)
{
    const int lane = threadIdx.x & 63;
    const int wid  = threadIdx.x >> 6;
    const int n    = blockIdx.x * 4 + wid;
    if (n >= N_NODES) return;

    const float hn = (deg[n] > 0.0f) ? agg[n * F + lane] : h[n * F + lane];
    float p0 = hn * W_out[lane * NCLS + 0];
    float p1 = hn * W_out[lane * NCLS + 1];
    #pragma unroll
    for (int off = 32; off > 0; off >>= 1) {
        p0 += __shfl_xor(p0, off);
        p1 += __shfl_xor(p1, off);
    }
    if (lane == 0) {
        out[n * NCLS + 0] = p0 + b_out[0];
        out[n * NCLS + 1] = p1 + b_out[1];
    }
}

// ---------------------------------------------------------------------------
extern "C" void kernel_launch(void* const* d_in, const int* in_sizes, int n_in,
                              void* d_out, int out_size, void* d_ws, size_t ws_size,
                              hipStream_t stream) {
    const float* feat   = (const float*)d_in[0];
    const int*   src    = (const int*)d_in[1];
    const int*   dst    = (const int*)d_in[2];
    const float* W_in   = (const float*)d_in[3];
    const float* b_in   = (const float*)d_in[4];
    const float* W_edge = (const float*)d_in[5];
    const float* b_edge = (const float*)d_in[6];
    const float* W_out  = (const float*)d_in[7];
    const float* b_out  = (const float*)d_in[8];
    float* out = (float*)d_out;

    // workspace layout (floats)
    float* ws   = (float*)d_ws;
    float* h    = ws;                               // N*64
    float* agg  = h + (size_t)N_NODES * F;          // N*64
    float* A    = agg + (size_t)N_NODES * F;        // N
    float* B    = A + N_NODES;                      // N
    float* deg  = B + N_NODES;                      // N

    // zero the accumulators (ws is poisoned to 0xAA before every launch)
    hipMemsetAsync(agg, 0, (size_t)N_NODES * F * sizeof(float), stream);
    hipMemsetAsync(deg, 0, (size_t)N_NODES * sizeof(float), stream);

    const int blocks_nodes = (N_NODES + 3) / 4;  // 4 nodes (waves) per block
    node_mlp_kernel<<<blocks_nodes, 256, 0, stream>>>(feat, W_in, b_in, W_edge, h, A, B);

    edge_scatter_kernel<<<4096, 256, 0, stream>>>(src, dst, h, A, B, b_edge, agg, deg);

    out_kernel<<<blocks_nodes, 256, 0, stream>>>(h, agg, deg, W_out, b_out, out);
}

// Round 2
// 511.729 us; speedup vs baseline: 1.2534x; 1.2534x over previous
//
#include <hip/hip_runtime.h>
#include <hip/hip_bf16.h>
#include <math.h>

#define N_NODES 100000
#define N_EDGES 1600000
#define F 64          // IN_FEATS == HIDDEN == 64
#define NCLS 2
#define CHUNK 1024
#define NCHUNK ((N_NODES + CHUNK - 1) / CHUNK)   // 98

// ---------------------------------------------------------------------------
// K1: h = feat @ W_in + b_in ; A[n] = h[n]·W_u ; B[n] = h[n]·W_v
// One wave per node, W_in staged in LDS, feat broadcast via shfl.
// ---------------------------------------------------------------------------
__global__ __launch_bounds__(256) void node_mlp_kernel(
    const float* __restrict__ feat,
    const float* __restrict__ W_in,
    const float* __restrict__ b_in,
    const float* __restrict__ W_edge,
    float* __restrict__ h,
    float* __restrict__ A,
    float* __restrict__ B)
{
    __shared__ float sW[F * F];
    __shared__ float sWu[F];
    __shared__ float sWv[F];
    __shared__ float sb[F];

    for (int i = threadIdx.x; i < F * F; i += 256) sW[i] = W_in[i];
    if (threadIdx.x < F) {
        sWu[threadIdx.x] = W_edge[threadIdx.x];
        sWv[threadIdx.x] = W_edge[F + threadIdx.x];
        sb[threadIdx.x]  = b_in[threadIdx.x];
    }
    __syncthreads();

    const int lane = threadIdx.x & 63;
    const int wid  = threadIdx.x >> 6;
    const int n    = blockIdx.x * 4 + wid;
    if (n >= N_NODES) return;

    const float f = feat[n * F + lane];
    float acc = sb[lane];
    #pragma unroll
    for (int k = 0; k < F; ++k) {
        acc += __shfl(f, k) * sW[k * F + lane];
    }

    float au = acc * sWu[lane];
    float av = acc * sWv[lane];
    #pragma unroll
    for (int off = 32; off > 0; off >>= 1) {
        au += __shfl_xor(au, off);
        av += __shfl_xor(av, off);
    }

    h[n * F + lane] = acc;
    if (lane == 0) { A[n] = au; B[n] = av; }
}

// ---------------------------------------------------------------------------
// K2: histogram deg_i[dst]++
// ---------------------------------------------------------------------------
__global__ __launch_bounds__(256) void hist_kernel(
    const int* __restrict__ dst, int* __restrict__ deg_i)
{
    int e = blockIdx.x * 256 + threadIdx.x;
    if (e < N_EDGES) atomicAdd(&deg_i[dst[e]], 1);
}

// ---------------------------------------------------------------------------
// K3a: per-chunk sums of deg_i (CHUNK=1024 nodes per block)
// ---------------------------------------------------------------------------
__global__ __launch_bounds__(256) void chunk_sum_kernel(
    const int* __restrict__ deg_i, int* __restrict__ chunk_sum)
{
    const int b = blockIdx.x;
    const int base = b * CHUNK;
    int s = 0;
    for (int i = threadIdx.x; i < CHUNK; i += 256) {
        int n = base + i;
        if (n < N_NODES) s += deg_i[n];
    }
    #pragma unroll
    for (int off = 32; off > 0; off >>= 1) s += __shfl_xor(s, off);
    __shared__ int red[4];
    if ((threadIdx.x & 63) == 0) red[threadIdx.x >> 6] = s;
    __syncthreads();
    if (threadIdx.x == 0) chunk_sum[b] = red[0] + red[1] + red[2] + red[3];
}

// ---------------------------------------------------------------------------
// K3b: exclusive scan of the 98 chunk sums (in LDS), + row_ptr[N]=E
// ---------------------------------------------------------------------------
__global__ __launch_bounds__(128) void scan_chunks_kernel(
    int* __restrict__ chunk_sum, int* __restrict__ row_ptr)
{
    __shared__ int s[NCHUNK];
    if (threadIdx.x < NCHUNK) s[threadIdx.x] = chunk_sum[threadIdx.x];
    __syncthreads();
    if (threadIdx.x == 0) {
        int acc = 0;
        for (int i = 0; i < NCHUNK; ++i) { int v = s[i]; s[i] = acc; acc += v; }
        row_ptr[N_NODES] = N_EDGES;
    }
    __syncthreads();
    if (threadIdx.x < NCHUNK) chunk_sum[threadIdx.x] = s[threadIdx.x];
}

// ---------------------------------------------------------------------------
// K3c: per-chunk exclusive scan of deg_i -> row_ptr (+ cursor copy)
// ---------------------------------------------------------------------------
__global__ __launch_bounds__(256) void scan_nodes_kernel(
    const int* __restrict__ deg_i, const int* __restrict__ chunk_off,
    int* __restrict__ row_ptr, int* __restrict__ cursor)
{
    __shared__ int sdata[256];
    const int b = blockIdx.x;
    const int tbase = b * CHUNK + threadIdx.x * 4;

    int v[4];
    int tsum = 0;
    #pragma unroll
    for (int j = 0; j < 4; ++j) {
        int n = tbase + j;
        v[j] = (n < N_NODES) ? deg_i[n] : 0;
        tsum += v[j];
    }
    sdata[threadIdx.x] = tsum;
    __syncthreads();
    // Hillis-Steele inclusive scan over 256 thread sums
    for (int off = 1; off < 256; off <<= 1) {
        int t = (threadIdx.x >= off) ? sdata[threadIdx.x - off] : 0;
        __syncthreads();
        sdata[threadIdx.x] += t;
        __syncthreads();
    }
    int excl = chunk_off[b] + sdata[threadIdx.x] - tsum;
    #pragma unroll
    for (int j = 0; j < 4; ++j) {
        int n = tbase + j;
        if (n < N_NODES) { row_ptr[n] = excl; cursor[n] = excl; }
        excl += v[j];
    }
}

// ---------------------------------------------------------------------------
// K4: scatter edges into dst-sorted order
// ---------------------------------------------------------------------------
__global__ __launch_bounds__(256) void scatter_kernel(
    const int* __restrict__ src, const int* __restrict__ dst,
    int* __restrict__ cursor, int* __restrict__ src_sorted)
{
    int e = blockIdx.x * 256 + threadIdx.x;
    if (e < N_EDGES) {
        int d = dst[e];
        int pos = atomicAdd(&cursor[d], 1);
        src_sorted[pos] = src[e];
    }
}

// ---------------------------------------------------------------------------
// K5: per-node segmented reduction + fused output GEMV.
// Wave per node; lanes cooperatively load <=64 edges' src + gate weight,
// shfl-broadcast, accumulate h[s]*w in registers. Epilogue: @ W_out + b_out.
// ---------------------------------------------------------------------------
__global__ __launch_bounds__(256) void agg_out_kernel(
    const float* __restrict__ h,
    const float* __restrict__ A,
    const float* __restrict__ B,
    const float* __restrict__ b_edge,
    const int* __restrict__ row_ptr,
    const int* __restrict__ src_sorted,
    const float* __restrict__ W_out,
    const float* __restrict__ b_out,
    float* __restrict__ out)
{
    __shared__ float sWo[F * NCLS];
    __shared__ float sbo[NCLS];
    if (threadIdx.x < F * NCLS) sWo[threadIdx.x] = W_out[threadIdx.x];
    if (threadIdx.x < NCLS)     sbo[threadIdx.x] = b_out[threadIdx.x];
    __syncthreads();

    const int lane = threadIdx.x & 63;
    const int wid  = threadIdx.x >> 6;
    const int n    = blockIdx.x * 4 + wid;
    if (n >= N_NODES) return;

    const int beg = row_ptr[n];
    const int end = row_ptr[n + 1];

    float hn;
    if (end == beg) {
        hn = h[n * F + lane];          // isolated node: keep h
    } else {
        const float be = b_edge[0];
        const float Bn = B[n];
        float acc = 0.0f;
        for (int base = beg; base < end; base += 64) {
            const int m = min(64, end - base);
            int   sv = 0;
            float wv = 0.0f;
            if (lane < m) {
                sv = src_sorted[base + lane];
                float x = A[sv] + Bn + be;
                wv = 1.0f / (1.0f + __expf(-x));
            }
            for (int i = 0; i < m; ++i) {
                const int   s = __shfl(sv, i);
                const float w = __shfl(wv, i);
                acc += h[(size_t)s * F + lane] * w;
            }
        }
        hn = acc;
    }

    float p0 = hn * sWo[lane * NCLS + 0];
    float p1 = hn * sWo[lane * NCLS + 1];
    #pragma unroll
    for (int off = 32; off > 0; off >>= 1) {
        p0 += __shfl_xor(p0, off);
        p1 += __shfl_xor(p1, off);
    }
    if (lane == 0) {
        out[n * NCLS + 0] = p0 + sbo[0];
        out[n * NCLS + 1] = p1 + sbo[1];
    }
}

// ---------------------------------------------------------------------------
extern "C" void kernel_launch(void* const* d_in, const int* in_sizes, int n_in,
                              void* d_out, int out_size, void* d_ws, size_t ws_size,
                              hipStream_t stream) {
    const float* feat   = (const float*)d_in[0];
    const int*   src    = (const int*)d_in[1];
    const int*   dst    = (const int*)d_in[2];
    const float* W_in   = (const float*)d_in[3];
    const float* b_in   = (const float*)d_in[4];
    const float* W_edge = (const float*)d_in[5];
    const float* b_edge = (const float*)d_in[6];
    const float* W_out  = (const float*)d_in[7];
    const float* b_out  = (const float*)d_in[8];
    float* out = (float*)d_out;

    // workspace layout
    float* ws        = (float*)d_ws;
    float* h         = ws;                                  // N*64 f32
    int*   deg_i     = (int*)(h + (size_t)N_NODES * F);     // N
    int*   row_ptr   = deg_i + N_NODES;                     // N+1
    int*   cursor    = row_ptr + N_NODES + 1;               // N
    int*   chunk_sum = cursor + N_NODES;                    // NCHUNK (pad 128)
    int*   src_sorted= chunk_sum + 128;                     // E
    float* A         = (float*)(src_sorted + N_EDGES);      // N
    float* B         = A + N_NODES;                         // N

    hipMemsetAsync(deg_i, 0, (size_t)N_NODES * sizeof(int), stream);

    const int blocks_nodes = (N_NODES + 3) / 4;
    const int blocks_edges = (N_EDGES + 255) / 256;

    node_mlp_kernel<<<blocks_nodes, 256, 0, stream>>>(feat, W_in, b_in, W_edge, h, A, B);
    hist_kernel<<<blocks_edges, 256, 0, stream>>>(dst, deg_i);
    chunk_sum_kernel<<<NCHUNK, 256, 0, stream>>>(deg_i, chunk_sum);
    scan_chunks_kernel<<<1, 128, 0, stream>>>(chunk_sum, row_ptr);
    scan_nodes_kernel<<<NCHUNK, 256, 0, stream>>>(deg_i, chunk_sum, row_ptr, cursor);
    scatter_kernel<<<blocks_edges, 256, 0, stream>>>(src, dst, cursor, src_sorted);
    agg_out_kernel<<<blocks_nodes, 256, 0, stream>>>(h, A, B, b_edge, row_ptr, src_sorted,
                                                     W_out, b_out, out);
}

// Round 3
// 388.185 us; speedup vs baseline: 1.6524x; 1.3183x over previous
//
#include <hip/hip_runtime.h>
#include <hip/hip_bf16.h>
#include <math.h>

#define N_NODES 100000
#define N_EDGES 1600000
#define F 64          // IN_FEATS == HIDDEN == 64
#define NCLS 2

#define BW_LOG 7
#define BW 128                               // nodes per bucket
#define NB ((N_NODES + BW - 1) / BW)         // 782 buckets
#define EPB (N_EDGES / 256)                  // 6250 edges per bin block (exact)

// ---------------------------------------------------------------------------
// K1: h = feat @ W_in + b_in ; A[n] = h[n]·W_u ; B[n] = h[n]·W_v
// ---------------------------------------------------------------------------
__global__ __launch_bounds__(256) void node_mlp_kernel(
    const float* __restrict__ feat,
    const float* __restrict__ W_in,
    const float* __restrict__ b_in,
    const float* __restrict__ W_edge,
    float* __restrict__ h,
    float* __restrict__ A,
    float* __restrict__ B)
{
    __shared__ float sW[F * F];
    __shared__ float sWu[F];
    __shared__ float sWv[F];
    __shared__ float sb[F];

    for (int i = threadIdx.x; i < F * F; i += 256) sW[i] = W_in[i];
    if (threadIdx.x < F) {
        sWu[threadIdx.x] = W_edge[threadIdx.x];
        sWv[threadIdx.x] = W_edge[F + threadIdx.x];
        sb[threadIdx.x]  = b_in[threadIdx.x];
    }
    __syncthreads();

    const int lane = threadIdx.x & 63;
    const int wid  = threadIdx.x >> 6;
    const int n    = blockIdx.x * 4 + wid;
    if (n >= N_NODES) return;

    const float f = feat[n * F + lane];
    float acc = sb[lane];
    #pragma unroll
    for (int k = 0; k < F; ++k) {
        acc += __shfl(f, k) * sW[k * F + lane];
    }

    float au = acc * sWu[lane];
    float av = acc * sWv[lane];
    #pragma unroll
    for (int off = 32; off > 0; off >>= 1) {
        au += __shfl_xor(au, off);
        av += __shfl_xor(av, off);
    }

    h[n * F + lane] = acc;
    if (lane == 0) { A[n] = au; B[n] = av; }
}

// ---------------------------------------------------------------------------
// K2: coarse bucket histogram (LDS per block, one global atomic per
// (block,bucket)).
// ---------------------------------------------------------------------------
__global__ __launch_bounds__(256) void bin_count_kernel(
    const int* __restrict__ dst, int* __restrict__ bucket_cnt)
{
    __shared__ int hist[NB];
    for (int i = threadIdx.x; i < NB; i += 256) hist[i] = 0;
    __syncthreads();

    const int beg = blockIdx.x * EPB;
    const int end = beg + EPB;
    for (int e = beg + threadIdx.x; e < end; e += 256)
        atomicAdd(&hist[dst[e] >> BW_LOG], 1);
    __syncthreads();

    for (int b = threadIdx.x; b < NB; b += 256)
        if (hist[b]) atomicAdd(&bucket_cnt[b], hist[b]);
}

// ---------------------------------------------------------------------------
// K3: exclusive scan of 782 bucket counts (single block, Hillis-Steele).
// Produces bucket_base[NB+1] and initializes bucket_cursor.
// ---------------------------------------------------------------------------
__global__ __launch_bounds__(1024) void bucket_scan_kernel(
    const int* __restrict__ bucket_cnt,
    int* __restrict__ bucket_base,
    int* __restrict__ bucket_cursor,
    int* __restrict__ row_ptr)
{
    __shared__ int s[1024];
    const int t = threadIdx.x;
    const int v = (t < NB) ? bucket_cnt[t] : 0;
    s[t] = v;
    __syncthreads();
    for (int off = 1; off < 1024; off <<= 1) {
        int tv = (t >= off) ? s[t - off] : 0;
        __syncthreads();
        s[t] += tv;
        __syncthreads();
    }
    if (t < NB) {
        const int excl = s[t] - v;
        bucket_base[t]   = excl;
        bucket_cursor[t] = excl;
    }
    if (t == 0) {
        bucket_base[NB]    = N_EDGES;
        row_ptr[N_NODES]   = N_EDGES;
    }
}

// ---------------------------------------------------------------------------
// K4: bin scatter — rank edges within (block,bucket) in LDS, reserve a
// contiguous run per bucket with ONE global atomic, write (src,dst) pairs
// into the run (same-line writes stay within one block/XCD).
// ---------------------------------------------------------------------------
__global__ __launch_bounds__(256) void bin_scatter_kernel(
    const int* __restrict__ src, const int* __restrict__ dst,
    int* __restrict__ bucket_cursor, int2* __restrict__ pairs)
{
    __shared__ int hist[NB];
    __shared__ int base[NB];
    for (int i = threadIdx.x; i < NB; i += 256) hist[i] = 0;
    __syncthreads();

    const int beg = blockIdx.x * EPB;
    const int end = beg + EPB;
    for (int e = beg + threadIdx.x; e < end; e += 256)
        atomicAdd(&hist[dst[e] >> BW_LOG], 1);
    __syncthreads();

    for (int b = threadIdx.x; b < NB; b += 256) {
        if (hist[b]) base[b] = atomicAdd(&bucket_cursor[b], hist[b]);
        hist[b] = 0;   // reuse as rank counter
    }
    __syncthreads();

    for (int e = beg + threadIdx.x; e < end; e += 256) {
        const int d = dst[e];
        const int b = d >> BW_LOG;
        const int r = atomicAdd(&hist[b], 1);
        pairs[base[b] + r] = make_int2(src[e], d);
    }
}

// ---------------------------------------------------------------------------
// K5: fine sort — one block per bucket (128 nodes). Count per-node degree in
// LDS, scan, emit row_ptr (coalesced) and place src into src_sorted within
// the bucket's contiguous region.
// ---------------------------------------------------------------------------
__global__ __launch_bounds__(256) void fine_sort_kernel(
    const int2* __restrict__ pairs,
    const int* __restrict__ bucket_base,
    int* __restrict__ row_ptr,
    int* __restrict__ src_sorted)
{
    __shared__ int cntA[BW];
    __shared__ int cntS[BW];
    __shared__ int rowb[BW];

    const int b   = blockIdx.x;
    const int tid = threadIdx.x;
    const int ebeg = bucket_base[b];
    const int eend = bucket_base[b + 1];

    if (tid < BW) cntA[tid] = 0;
    __syncthreads();

    for (int i = ebeg + tid; i < eend; i += 256)
        atomicAdd(&cntA[pairs[i].y & (BW - 1)], 1);
    __syncthreads();

    // inclusive scan over BW=128 counters
    int v = 0;
    if (tid < BW) { v = cntA[tid]; cntS[tid] = v; }
    __syncthreads();
    for (int off = 1; off < BW; off <<= 1) {
        int tv = 0;
        if (tid < BW && tid >= off) tv = cntS[tid - off];
        __syncthreads();
        if (tid < BW) cntS[tid] += tv;
        __syncthreads();
    }

    if (tid < BW) {
        const int excl = cntS[tid] - v;
        rowb[tid] = ebeg + excl;
        const int n = b * BW + tid;
        if (n < N_NODES) row_ptr[n] = ebeg + excl;
        cntA[tid] = 0;   // reuse as placement rank
    }
    __syncthreads();

    for (int i = ebeg + tid; i < eend; i += 256) {
        const int2 p = pairs[i];
        const int dl = p.y & (BW - 1);
        const int r = atomicAdd(&cntA[dl], 1);
        src_sorted[rowb[dl] + r] = p.x;
    }
}

// ---------------------------------------------------------------------------
// K6: per-node segmented reduction + fused output GEMV.
// ---------------------------------------------------------------------------
__global__ __launch_bounds__(256) void agg_out_kernel(
    const float* __restrict__ h,
    const float* __restrict__ A,
    const float* __restrict__ B,
    const float* __restrict__ b_edge,
    const int* __restrict__ row_ptr,
    const int* __restrict__ src_sorted,
    const float* __restrict__ W_out,
    const float* __restrict__ b_out,
    float* __restrict__ out)
{
    __shared__ float sWo[F * NCLS];
    __shared__ float sbo[NCLS];
    if (threadIdx.x < F * NCLS) sWo[threadIdx.x] = W_out[threadIdx.x];
    if (threadIdx.x < NCLS)     sbo[threadIdx.x] = b_out[threadIdx.x];
    __syncthreads();

    const int lane = threadIdx.x & 63;
    const int wid  = threadIdx.x >> 6;
    const int n    = blockIdx.x * 4 + wid;
    if (n >= N_NODES) return;

    const int beg = row_ptr[n];
    const int end = row_ptr[n + 1];

    float hn;
    if (end == beg) {
        hn = h[n * F + lane];          // isolated node: keep h
    } else {
        const float be = b_edge[0];
        const float Bn = B[n];
        float acc = 0.0f;
        for (int base = beg; base < end; base += 64) {
            const int m = min(64, end - base);
            int   sv = 0;
            float wv = 0.0f;
            if (lane < m) {
                sv = src_sorted[base + lane];
                float x = A[sv] + Bn + be;
                wv = 1.0f / (1.0f + __expf(-x));
            }
            for (int i = 0; i < m; ++i) {
                const int   s = __shfl(sv, i);
                const float w = __shfl(wv, i);
                acc += h[(size_t)s * F + lane] * w;
            }
        }
        hn = acc;
    }

    float p0 = hn * sWo[lane * NCLS + 0];
    float p1 = hn * sWo[lane * NCLS + 1];
    #pragma unroll
    for (int off = 32; off > 0; off >>= 1) {
        p0 += __shfl_xor(p0, off);
        p1 += __shfl_xor(p1, off);
    }
    if (lane == 0) {
        out[n * NCLS + 0] = p0 + sbo[0];
        out[n * NCLS + 1] = p1 + sbo[1];
    }
}

// ---------------------------------------------------------------------------
extern "C" void kernel_launch(void* const* d_in, const int* in_sizes, int n_in,
                              void* d_out, int out_size, void* d_ws, size_t ws_size,
                              hipStream_t stream) {
    const float* feat   = (const float*)d_in[0];
    const int*   src    = (const int*)d_in[1];
    const int*   dst    = (const int*)d_in[2];
    const float* W_in   = (const float*)d_in[3];
    const float* b_in   = (const float*)d_in[4];
    const float* W_edge = (const float*)d_in[5];
    const float* b_edge = (const float*)d_in[6];
    const float* W_out  = (const float*)d_in[7];
    const float* b_out  = (const float*)d_in[8];
    float* out = (float*)d_out;

    // workspace layout
    float* ws            = (float*)d_ws;
    float* h             = ws;                                   // N*F f32
    float* A             = h + (size_t)N_NODES * F;              // N
    float* B             = A + N_NODES;                          // N
    int*   row_ptr       = (int*)(B + N_NODES);                  // N+1
    int*   bucket_cnt    = row_ptr + N_NODES + 1;                // NB
    int*   bucket_base   = bucket_cnt + NB;                      // NB+1
    int*   bucket_cursor = bucket_base + NB + 1;                 // NB
    int*   src_sorted    = bucket_cursor + NB;                   // E
    int2*  pairs         = (int2*)(src_sorted + N_EDGES);        // E (8B each)

    hipMemsetAsync(bucket_cnt, 0, NB * sizeof(int), stream);

    const int blocks_nodes = (N_NODES + 3) / 4;

    node_mlp_kernel<<<blocks_nodes, 256, 0, stream>>>(feat, W_in, b_in, W_edge, h, A, B);
    bin_count_kernel<<<256, 256, 0, stream>>>(dst, bucket_cnt);
    bucket_scan_kernel<<<1, 1024, 0, stream>>>(bucket_cnt, bucket_base, bucket_cursor, row_ptr);
    bin_scatter_kernel<<<256, 256, 0, stream>>>(src, dst, bucket_cursor, pairs);
    fine_sort_kernel<<<NB, 256, 0, stream>>>(pairs, bucket_base, row_ptr, src_sorted);
    agg_out_kernel<<<blocks_nodes, 256, 0, stream>>>(h, A, B, b_edge, row_ptr, src_sorted,
                                                     W_out, b_out, out);
}

// Round 4
// 288.163 us; speedup vs baseline: 2.2259x; 1.3471x over previous
//
#include <hip/hip_runtime.h>
#include <hip/hip_bf16.h>
#include <math.h>

#define N_NODES 100000
#define N_EDGES 1600000
#define F 64          // IN_FEATS == HIDDEN == 64
#define NCLS 2

#define BW_LOG 7
#define BW 128                               // nodes per bucket
#define NB ((N_NODES + BW - 1) / BW)         // 782 buckets
#define EPB (N_EDGES / 256)                  // 6250 edges per bin block (exact)

#define TM 64                                // nodes per node_mlp block
#define STRIDE 68                            // padded LDS row stride (floats)

// ---------------------------------------------------------------------------
// K1: h = feat @ W_in + b_in ; A[n] = h[n]·W_u ; B[n] = h[n]·W_v
// Register-tiled GEMM: 64 nodes x 64 cols per block, 4x4 micro-tile/thread.
// feat staged transposed in LDS (sT[k][node], stride 68 -> aligned b128,
// conflict-free reads). W_in staged row-major (b128 reads, 2-way = free).
// ---------------------------------------------------------------------------
__global__ __launch_bounds__(256) void node_mlp_kernel(
    const float* __restrict__ feat,
    const float* __restrict__ W_in,
    const float* __restrict__ b_in,
    const float* __restrict__ W_edge,
    float* __restrict__ h,
    float* __restrict__ A,
    float* __restrict__ B)
{
    __shared__ float sT[F * STRIDE];   // feat^T tile: sT[k*STRIDE + node]
    __shared__ float sW[F * F];        // W_in row-major
    __shared__ float sWu[F];
    __shared__ float sWv[F];

    const int tid = threadIdx.x;
    const int tx  = tid & 15;          // col group: cols tx*4 .. tx*4+3
    const int ty  = tid >> 4;          // node group: nodes ty*4 .. ty*4+3
    const int n0  = blockIdx.x * TM;

    for (int i = tid; i < F * F; i += 256) sW[i] = W_in[i];
    if (tid < F) { sWu[tid] = W_edge[tid]; sWv[tid] = W_edge[F + tid]; }

    // stage feat transposed: pass p, thread t -> node = p*16 + (t>>4), k4 = (t&15)*4
    #pragma unroll
    for (int p = 0; p < 4; ++p) {
        const int node = p * 16 + ty;
        const int k4   = tx * 4;
        const int n    = n0 + node;
        float4 v = make_float4(0.f, 0.f, 0.f, 0.f);
        if (n < N_NODES) v = *(const float4*)&feat[(size_t)n * F + k4];
        sT[(k4 + 0) * STRIDE + node] = v.x;
        sT[(k4 + 1) * STRIDE + node] = v.y;
        sT[(k4 + 2) * STRIDE + node] = v.z;
        sT[(k4 + 3) * STRIDE + node] = v.w;
    }
    __syncthreads();

    // init accumulators with bias
    const float4 bb = *(const float4*)&b_in[tx * 4];
    float acc[4][4];
    #pragma unroll
    for (int i = 0; i < 4; ++i) {
        acc[i][0] = bb.x; acc[i][1] = bb.y; acc[i][2] = bb.z; acc[i][3] = bb.w;
    }

    // k-loop: 2 x b128 LDS reads -> 16 FMAs
    #pragma unroll 4
    for (int k = 0; k < F; ++k) {
        const float4 a = *(const float4*)&sT[k * STRIDE + ty * 4];
        const float4 b = *(const float4*)&sW[k * F + tx * 4];
        const float av_[4] = {a.x, a.y, a.z, a.w};
        const float bv_[4] = {b.x, b.y, b.z, b.w};
        #pragma unroll
        for (int i = 0; i < 4; ++i)
            #pragma unroll
            for (int j = 0; j < 4; ++j)
                acc[i][j] += av_[i] * bv_[j];
    }

    // gate scalars: partial dot over this thread's 4 cols, butterfly over 16 lanes
    const float wu0 = sWu[tx * 4 + 0], wu1 = sWu[tx * 4 + 1],
                wu2 = sWu[tx * 4 + 2], wu3 = sWu[tx * 4 + 3];
    const float wv0 = sWv[tx * 4 + 0], wv1 = sWv[tx * 4 + 1],
                wv2 = sWv[tx * 4 + 2], wv3 = sWv[tx * 4 + 3];

    #pragma unroll
    for (int i = 0; i < 4; ++i) {
        const int n = n0 + ty * 4 + i;
        float pa = acc[i][0] * wu0 + acc[i][1] * wu1 + acc[i][2] * wu2 + acc[i][3] * wu3;
        float pb = acc[i][0] * wv0 + acc[i][1] * wv1 + acc[i][2] * wv2 + acc[i][3] * wv3;
        #pragma unroll
        for (int off = 8; off > 0; off >>= 1) {
            pa += __shfl_xor(pa, off);
            pb += __shfl_xor(pb, off);
        }
        if (n < N_NODES) {
            float4 st = make_float4(acc[i][0], acc[i][1], acc[i][2], acc[i][3]);
            *(float4*)&h[(size_t)n * F + tx * 4] = st;
            if (tx == 0) { A[n] = pa; B[n] = pb; }
        }
    }
}

// ---------------------------------------------------------------------------
// K2: coarse bucket histogram (LDS per block, one global atomic per
// (block,bucket)).
// ---------------------------------------------------------------------------
__global__ __launch_bounds__(256) void bin_count_kernel(
    const int* __restrict__ dst, int* __restrict__ bucket_cnt)
{
    __shared__ int hist[NB];
    for (int i = threadIdx.x; i < NB; i += 256) hist[i] = 0;
    __syncthreads();

    const int beg = blockIdx.x * EPB;
    const int end = beg + EPB;
    for (int e = beg + threadIdx.x; e < end; e += 256)
        atomicAdd(&hist[dst[e] >> BW_LOG], 1);
    __syncthreads();

    for (int b = threadIdx.x; b < NB; b += 256)
        if (hist[b]) atomicAdd(&bucket_cnt[b], hist[b]);
}

// ---------------------------------------------------------------------------
// K3: exclusive scan of 782 bucket counts (single block, Hillis-Steele).
// ---------------------------------------------------------------------------
__global__ __launch_bounds__(1024) void bucket_scan_kernel(
    const int* __restrict__ bucket_cnt,
    int* __restrict__ bucket_base,
    int* __restrict__ bucket_cursor,
    int* __restrict__ row_ptr)
{
    __shared__ int s[1024];
    const int t = threadIdx.x;
    const int v = (t < NB) ? bucket_cnt[t] : 0;
    s[t] = v;
    __syncthreads();
    for (int off = 1; off < 1024; off <<= 1) {
        int tv = (t >= off) ? s[t - off] : 0;
        __syncthreads();
        s[t] += tv;
        __syncthreads();
    }
    if (t < NB) {
        const int excl = s[t] - v;
        bucket_base[t]   = excl;
        bucket_cursor[t] = excl;
    }
    if (t == 0) {
        bucket_base[NB]  = N_EDGES;
        row_ptr[N_NODES] = N_EDGES;
    }
}

// ---------------------------------------------------------------------------
// K4: bin scatter — rank edges within (block,bucket) in LDS, reserve a
// contiguous run per bucket with ONE global atomic, write (src,dst) pairs.
// ---------------------------------------------------------------------------
__global__ __launch_bounds__(256) void bin_scatter_kernel(
    const int* __restrict__ src, const int* __restrict__ dst,
    int* __restrict__ bucket_cursor, int2* __restrict__ pairs)
{
    __shared__ int hist[NB];
    __shared__ int base[NB];
    for (int i = threadIdx.x; i < NB; i += 256) hist[i] = 0;
    __syncthreads();

    const int beg = blockIdx.x * EPB;
    const int end = beg + EPB;
    for (int e = beg + threadIdx.x; e < end; e += 256)
        atomicAdd(&hist[dst[e] >> BW_LOG], 1);
    __syncthreads();

    for (int b = threadIdx.x; b < NB; b += 256) {
        if (hist[b]) base[b] = atomicAdd(&bucket_cursor[b], hist[b]);
        hist[b] = 0;   // reuse as rank counter
    }
    __syncthreads();

    for (int e = beg + threadIdx.x; e < end; e += 256) {
        const int d = dst[e];
        const int b = d >> BW_LOG;
        const int r = atomicAdd(&hist[b], 1);
        pairs[base[b] + r] = make_int2(src[e], d);
    }
}

// ---------------------------------------------------------------------------
// K5: fine sort — one block per bucket (128 nodes): count, scan, emit
// row_ptr and src_sorted within the bucket's contiguous region.
// ---------------------------------------------------------------------------
__global__ __launch_bounds__(256) void fine_sort_kernel(
    const int2* __restrict__ pairs,
    const int* __restrict__ bucket_base,
    int* __restrict__ row_ptr,
    int* __restrict__ src_sorted)
{
    __shared__ int cntA[BW];
    __shared__ int cntS[BW];
    __shared__ int rowb[BW];

    const int b   = blockIdx.x;
    const int tid = threadIdx.x;
    const int ebeg = bucket_base[b];
    const int eend = bucket_base[b + 1];

    if (tid < BW) cntA[tid] = 0;
    __syncthreads();

    for (int i = ebeg + tid; i < eend; i += 256)
        atomicAdd(&cntA[pairs[i].y & (BW - 1)], 1);
    __syncthreads();

    int v = 0;
    if (tid < BW) { v = cntA[tid]; cntS[tid] = v; }
    __syncthreads();
    for (int off = 1; off < BW; off <<= 1) {
        int tv = 0;
        if (tid < BW && tid >= off) tv = cntS[tid - off];
        __syncthreads();
        if (tid < BW) cntS[tid] += tv;
        __syncthreads();
    }

    if (tid < BW) {
        const int excl = cntS[tid] - v;
        rowb[tid] = ebeg + excl;
        const int n = b * BW + tid;
        if (n < N_NODES) row_ptr[n] = ebeg + excl;
        cntA[tid] = 0;   // reuse as placement rank
    }
    __syncthreads();

    for (int i = ebeg + tid; i < eend; i += 256) {
        const int2 p = pairs[i];
        const int dl = p.y & (BW - 1);
        const int r = atomicAdd(&cntA[dl], 1);
        src_sorted[rowb[dl] + r] = p.x;
    }
}

// ---------------------------------------------------------------------------
// K6: per-node segmented reduction + fused output GEMV.
// ---------------------------------------------------------------------------
__global__ __launch_bounds__(256) void agg_out_kernel(
    const float* __restrict__ h,
    const float* __restrict__ A,
    const float* __restrict__ B,
    const float* __restrict__ b_edge,
    const int* __restrict__ row_ptr,
    const int* __restrict__ src_sorted,
    const float* __restrict__ W_out,
    const float* __restrict__ b_out,
    float* __restrict__ out)
{
    __shared__ float sWo[F * NCLS];
    __shared__ float sbo[NCLS];
    if (threadIdx.x < F * NCLS) sWo[threadIdx.x] = W_out[threadIdx.x];
    if (threadIdx.x < NCLS)     sbo[threadIdx.x] = b_out[threadIdx.x];
    __syncthreads();

    const int lane = threadIdx.x & 63;
    const int wid  = threadIdx.x >> 6;
    const int n    = blockIdx.x * 4 + wid;
    if (n >= N_NODES) return;

    const int beg = row_ptr[n];
    const int end = row_ptr[n + 1];

    float hn;
    if (end == beg) {
        hn = h[n * F + lane];          // isolated node: keep h
    } else {
        const float be = b_edge[0];
        const float Bn = B[n];
        float acc = 0.0f;
        for (int base = beg; base < end; base += 64) {
            const int m = min(64, end - base);
            int   sv = 0;
            float wv = 0.0f;
            if (lane < m) {
                sv = src_sorted[base + lane];
                float x = A[sv] + Bn + be;
                wv = 1.0f / (1.0f + __expf(-x));
            }
            for (int i = 0; i < m; ++i) {
                const int   s = __shfl(sv, i);
                const float w = __shfl(wv, i);
                acc += h[(size_t)s * F + lane] * w;
            }
        }
        hn = acc;
    }

    float p0 = hn * sWo[lane * NCLS + 0];
    float p1 = hn * sWo[lane * NCLS + 1];
    #pragma unroll
    for (int off = 32; off > 0; off >>= 1) {
        p0 += __shfl_xor(p0, off);
        p1 += __shfl_xor(p1, off);
    }
    if (lane == 0) {
        out[n * NCLS + 0] = p0 + sbo[0];
        out[n * NCLS + 1] = p1 + sbo[1];
    }
}

// ---------------------------------------------------------------------------
extern "C" void kernel_launch(void* const* d_in, const int* in_sizes, int n_in,
                              void* d_out, int out_size, void* d_ws, size_t ws_size,
                              hipStream_t stream) {
    const float* feat   = (const float*)d_in[0];
    const int*   src    = (const int*)d_in[1];
    const int*   dst    = (const int*)d_in[2];
    const float* W_in   = (const float*)d_in[3];
    const float* b_in   = (const float*)d_in[4];
    const float* W_edge = (const float*)d_in[5];
    const float* b_edge = (const float*)d_in[6];
    const float* W_out  = (const float*)d_in[7];
    const float* b_out  = (const float*)d_in[8];
    float* out = (float*)d_out;

    // workspace layout
    float* ws            = (float*)d_ws;
    float* h             = ws;                                   // N*F f32
    float* A             = h + (size_t)N_NODES * F;              // N
    float* B             = A + N_NODES;                          // N
    int*   row_ptr       = (int*)(B + N_NODES);                  // N+1
    int*   bucket_cnt    = row_ptr + N_NODES + 1;                // NB
    int*   bucket_base   = bucket_cnt + NB;                      // NB+1
    int*   bucket_cursor = bucket_base + NB + 1;                 // NB
    int*   src_sorted    = bucket_cursor + NB;                   // E
    int2*  pairs         = (int2*)(src_sorted + N_EDGES);        // E (8B each)

    hipMemsetAsync(bucket_cnt, 0, NB * sizeof(int), stream);

    const int blocks_mlp   = (N_NODES + TM - 1) / TM;
    const int blocks_nodes = (N_NODES + 3) / 4;

    node_mlp_kernel<<<blocks_mlp, 256, 0, stream>>>(feat, W_in, b_in, W_edge, h, A, B);
    bin_count_kernel<<<256, 256, 0, stream>>>(dst, bucket_cnt);
    bucket_scan_kernel<<<1, 1024, 0, stream>>>(bucket_cnt, bucket_base, bucket_cursor, row_ptr);
    bin_scatter_kernel<<<256, 256, 0, stream>>>(src, dst, bucket_cursor, pairs);
    fine_sort_kernel<<<NB, 256, 0, stream>>>(pairs, bucket_base, row_ptr, src_sorted);
    agg_out_kernel<<<blocks_nodes, 256, 0, stream>>>(h, A, B, b_edge, row_ptr, src_sorted,
                                                     W_out, b_out, out);
}

// Round 5
// 234.041 us; speedup vs baseline: 2.7406x; 1.2312x over previous
//
#include <hip/hip_runtime.h>
#include <hip/hip_bf16.h>
#include <math.h>

#define N_NODES 100000
#define N_EDGES 1600000
#define F 64          // IN_FEATS == HIDDEN == 64
#define NCLS 2

#define BW_LOG 7
#define BW 128                               // nodes per bucket
#define NB ((N_NODES + BW - 1) / BW)         // 782 buckets
#define EPB (N_EDGES / 256)                  // 6250 edges per bin block (exact)

#define TM 64                                // nodes per node_mlp block
#define STRIDE 68                            // padded LDS row stride (floats)

typedef unsigned short u16;

__device__ __forceinline__ u16 f2bf(float x) {
    unsigned u = __float_as_uint(x);
    return (u16)((u + 0x7FFFu + ((u >> 16) & 1u)) >> 16);   // RNE
}
__device__ __forceinline__ float bf2f(u16 u) {
    return __uint_as_float(((unsigned)u) << 16);
}

// ---------------------------------------------------------------------------
// K1: h = feat @ W_in + b_in (stored as bf16) ; A[n]=h·W_u ; B[n]=h·W_v
// Register-tiled fp32 GEMM, 64x64 tile, 4x4 micro-tile per thread.
// ---------------------------------------------------------------------------
__global__ __launch_bounds__(256) void node_mlp_kernel(
    const float* __restrict__ feat,
    const float* __restrict__ W_in,
    const float* __restrict__ b_in,
    const float* __restrict__ W_edge,
    u16*   __restrict__ h16,
    float* __restrict__ A,
    float* __restrict__ B)
{
    __shared__ float sT[F * STRIDE];   // feat^T tile: sT[k*STRIDE + node]
    __shared__ float sW[F * F];        // W_in row-major
    __shared__ float sWu[F];
    __shared__ float sWv[F];

    const int tid = threadIdx.x;
    const int tx  = tid & 15;          // col group: cols tx*4 .. tx*4+3
    const int ty  = tid >> 4;          // node group: nodes ty*4 .. ty*4+3
    const int n0  = blockIdx.x * TM;

    for (int i = tid; i < F * F; i += 256) sW[i] = W_in[i];
    if (tid < F) { sWu[tid] = W_edge[tid]; sWv[tid] = W_edge[F + tid]; }

    #pragma unroll
    for (int p = 0; p < 4; ++p) {
        const int node = p * 16 + ty;
        const int k4   = tx * 4;
        const int n    = n0 + node;
        float4 v = make_float4(0.f, 0.f, 0.f, 0.f);
        if (n < N_NODES) v = *(const float4*)&feat[(size_t)n * F + k4];
        sT[(k4 + 0) * STRIDE + node] = v.x;
        sT[(k4 + 1) * STRIDE + node] = v.y;
        sT[(k4 + 2) * STRIDE + node] = v.z;
        sT[(k4 + 3) * STRIDE + node] = v.w;
    }
    __syncthreads();

    const float4 bb = *(const float4*)&b_in[tx * 4];
    float acc[4][4];
    #pragma unroll
    for (int i = 0; i < 4; ++i) {
        acc[i][0] = bb.x; acc[i][1] = bb.y; acc[i][2] = bb.z; acc[i][3] = bb.w;
    }

    #pragma unroll 4
    for (int k = 0; k < F; ++k) {
        const float4 a = *(const float4*)&sT[k * STRIDE + ty * 4];
        const float4 b = *(const float4*)&sW[k * F + tx * 4];
        const float av_[4] = {a.x, a.y, a.z, a.w};
        const float bv_[4] = {b.x, b.y, b.z, b.w};
        #pragma unroll
        for (int i = 0; i < 4; ++i)
            #pragma unroll
            for (int j = 0; j < 4; ++j)
                acc[i][j] += av_[i] * bv_[j];
    }

    const float wu0 = sWu[tx * 4 + 0], wu1 = sWu[tx * 4 + 1],
                wu2 = sWu[tx * 4 + 2], wu3 = sWu[tx * 4 + 3];
    const float wv0 = sWv[tx * 4 + 0], wv1 = sWv[tx * 4 + 1],
                wv2 = sWv[tx * 4 + 2], wv3 = sWv[tx * 4 + 3];

    #pragma unroll
    for (int i = 0; i < 4; ++i) {
        const int n = n0 + ty * 4 + i;
        float pa = acc[i][0] * wu0 + acc[i][1] * wu1 + acc[i][2] * wu2 + acc[i][3] * wu3;
        float pb = acc[i][0] * wv0 + acc[i][1] * wv1 + acc[i][2] * wv2 + acc[i][3] * wv3;
        #pragma unroll
        for (int off = 8; off > 0; off >>= 1) {
            pa += __shfl_xor(pa, off);
            pb += __shfl_xor(pb, off);
        }
        if (n < N_NODES) {
            uint2 pk;
            pk.x = (unsigned)f2bf(acc[i][0]) | ((unsigned)f2bf(acc[i][1]) << 16);
            pk.y = (unsigned)f2bf(acc[i][2]) | ((unsigned)f2bf(acc[i][3]) << 16);
            *(uint2*)&h16[(size_t)n * F + tx * 4] = pk;
            if (tx == 0) { A[n] = pa; B[n] = pb; }
        }
    }
}

// ---------------------------------------------------------------------------
// K2: coarse bucket histogram (LDS per block, one global atomic per
// (block,bucket)).
// ---------------------------------------------------------------------------
__global__ __launch_bounds__(256) void bin_count_kernel(
    const int* __restrict__ dst, int* __restrict__ bucket_cnt)
{
    __shared__ int hist[NB];
    for (int i = threadIdx.x; i < NB; i += 256) hist[i] = 0;
    __syncthreads();

    const int beg = blockIdx.x * EPB;
    const int end = beg + EPB;
    for (int e = beg + threadIdx.x; e < end; e += 256)
        atomicAdd(&hist[dst[e] >> BW_LOG], 1);
    __syncthreads();

    for (int b = threadIdx.x; b < NB; b += 256)
        if (hist[b]) atomicAdd(&bucket_cnt[b], hist[b]);
}

// ---------------------------------------------------------------------------
// K3: exclusive scan of 782 bucket counts (single block, Hillis-Steele).
// ---------------------------------------------------------------------------
__global__ __launch_bounds__(1024) void bucket_scan_kernel(
    const int* __restrict__ bucket_cnt,
    int* __restrict__ bucket_base,
    int* __restrict__ bucket_cursor,
    int* __restrict__ row_ptr)
{
    __shared__ int s[1024];
    const int t = threadIdx.x;
    const int v = (t < NB) ? bucket_cnt[t] : 0;
    s[t] = v;
    __syncthreads();
    for (int off = 1; off < 1024; off <<= 1) {
        int tv = (t >= off) ? s[t - off] : 0;
        __syncthreads();
        s[t] += tv;
        __syncthreads();
    }
    if (t < NB) {
        const int excl = s[t] - v;
        bucket_base[t]   = excl;
        bucket_cursor[t] = excl;
    }
    if (t == 0) {
        bucket_base[NB]  = N_EDGES;
        row_ptr[N_NODES] = N_EDGES;
    }
}

// ---------------------------------------------------------------------------
// K4: bin scatter — rank edges within (block,bucket) in LDS, reserve a
// contiguous run per bucket with ONE global atomic, write (src,dst) pairs.
// ---------------------------------------------------------------------------
__global__ __launch_bounds__(256) void bin_scatter_kernel(
    const int* __restrict__ src, const int* __restrict__ dst,
    int* __restrict__ bucket_cursor, int2* __restrict__ pairs)
{
    __shared__ int hist[NB];
    __shared__ int base[NB];
    for (int i = threadIdx.x; i < NB; i += 256) hist[i] = 0;
    __syncthreads();

    const int beg = blockIdx.x * EPB;
    const int end = beg + EPB;
    for (int e = beg + threadIdx.x; e < end; e += 256)
        atomicAdd(&hist[dst[e] >> BW_LOG], 1);
    __syncthreads();

    for (int b = threadIdx.x; b < NB; b += 256) {
        if (hist[b]) base[b] = atomicAdd(&bucket_cursor[b], hist[b]);
        hist[b] = 0;   // reuse as rank counter
    }
    __syncthreads();

    for (int e = beg + threadIdx.x; e < end; e += 256) {
        const int d = dst[e];
        const int b = d >> BW_LOG;
        const int r = atomicAdd(&hist[b], 1);
        pairs[base[b] + r] = make_int2(src[e], d);
    }
}

// ---------------------------------------------------------------------------
// K5: fine sort — one block per bucket (128 nodes): count, scan, emit
// row_ptr and src_sorted within the bucket's contiguous region.
// ---------------------------------------------------------------------------
__global__ __launch_bounds__(256) void fine_sort_kernel(
    const int2* __restrict__ pairs,
    const int* __restrict__ bucket_base,
    int* __restrict__ row_ptr,
    int* __restrict__ src_sorted)
{
    __shared__ int cntA[BW];
    __shared__ int cntS[BW];
    __shared__ int rowb[BW];

    const int b   = blockIdx.x;
    const int tid = threadIdx.x;
    const int ebeg = bucket_base[b];
    const int eend = bucket_base[b + 1];

    if (tid < BW) cntA[tid] = 0;
    __syncthreads();

    for (int i = ebeg + tid; i < eend; i += 256)
        atomicAdd(&cntA[pairs[i].y & (BW - 1)], 1);
    __syncthreads();

    int v = 0;
    if (tid < BW) { v = cntA[tid]; cntS[tid] = v; }
    __syncthreads();
    for (int off = 1; off < BW; off <<= 1) {
        int tv = 0;
        if (tid < BW && tid >= off) tv = cntS[tid - off];
        __syncthreads();
        if (tid < BW) cntS[tid] += tv;
        __syncthreads();
    }

    if (tid < BW) {
        const int excl = cntS[tid] - v;
        rowb[tid] = ebeg + excl;
        const int n = b * BW + tid;
        if (n < N_NODES) row_ptr[n] = ebeg + excl;
        cntA[tid] = 0;   // reuse as placement rank
    }
    __syncthreads();

    for (int i = ebeg + tid; i < eend; i += 256) {
        const int2 p = pairs[i];
        const int dl = p.y & (BW - 1);
        const int r = atomicAdd(&cntA[dl], 1);
        src_sorted[rowb[dl] + r] = p.x;
    }
}

// ---------------------------------------------------------------------------
// K6: per-node segmented reduction + fused output GEMV.
// Per 64-edge chunk: vectorized gate computation, (index,w) staged in LDS,
// inner loop: b128 LDS broadcast + bf16 gather, 4 accumulators.
// ---------------------------------------------------------------------------
__global__ __launch_bounds__(256) void agg_out_kernel(
    const u16*   __restrict__ h16,
    const float* __restrict__ A,
    const float* __restrict__ B,
    const float* __restrict__ b_edge,
    const int*   __restrict__ row_ptr,
    const int*   __restrict__ src_sorted,
    const float* __restrict__ W_out,
    const float* __restrict__ b_out,
    float* __restrict__ out)
{
    __shared__ float sWo[F * NCLS];
    __shared__ float sbo[NCLS];
    __shared__ __align__(16) int2 sEW[4][64];   // per-wave: (src*F, w bits)

    if (threadIdx.x < F * NCLS) sWo[threadIdx.x] = W_out[threadIdx.x];
    if (threadIdx.x < NCLS)     sbo[threadIdx.x] = b_out[threadIdx.x];
    __syncthreads();

    const int lane = threadIdx.x & 63;
    const int wid  = threadIdx.x >> 6;
    const int n    = blockIdx.x * 4 + wid;
    if (n >= N_NODES) return;

    const int beg = row_ptr[n];
    const int end = row_ptr[n + 1];

    float hn;
    if (end == beg) {
        hn = bf2f(h16[(size_t)n * F + lane]);    // isolated node: keep h
    } else {
        const float be = b_edge[0];
        const float Bn = B[n];
        float a0 = 0.f, a1 = 0.f, a2 = 0.f, a3 = 0.f;
        for (int base = beg; base < end; base += 64) {
            const int m = min(64, end - base);
            if (lane < m) {
                const int sv = src_sorted[base + lane];
                const float x = A[sv] + Bn + be;
                const float w = 1.0f / (1.0f + __expf(-x));
                sEW[wid][lane] = make_int2(sv * F, __float_as_int(w));
            }
            int k = 0;
            for (; k + 4 <= m; k += 4) {
                const int4 p01 = *(const int4*)&sEW[wid][k];       // edges k,k+1
                const int4 p23 = *(const int4*)&sEW[wid][k + 2];   // edges k+2,k+3
                const float v0 = bf2f(h16[p01.x + lane]);
                const float v1 = bf2f(h16[p01.z + lane]);
                const float v2 = bf2f(h16[p23.x + lane]);
                const float v3 = bf2f(h16[p23.z + lane]);
                a0 += v0 * __int_as_float(p01.y);
                a1 += v1 * __int_as_float(p01.w);
                a2 += v2 * __int_as_float(p23.y);
                a3 += v3 * __int_as_float(p23.w);
            }
            for (; k < m; ++k) {
                const int2 e = sEW[wid][k];
                a0 += bf2f(h16[e.x + lane]) * __int_as_float(e.y);
            }
        }
        hn = (a0 + a1) + (a2 + a3);
    }

    float p0 = hn * sWo[lane * NCLS + 0];
    float p1 = hn * sWo[lane * NCLS + 1];
    #pragma unroll
    for (int off = 32; off > 0; off >>= 1) {
        p0 += __shfl_xor(p0, off);
        p1 += __shfl_xor(p1, off);
    }
    if (lane == 0) {
        out[n * NCLS + 0] = p0 + sbo[0];
        out[n * NCLS + 1] = p1 + sbo[1];
    }
}

// ---------------------------------------------------------------------------
extern "C" void kernel_launch(void* const* d_in, const int* in_sizes, int n_in,
                              void* d_out, int out_size, void* d_ws, size_t ws_size,
                              hipStream_t stream) {
    const float* feat   = (const float*)d_in[0];
    const int*   src    = (const int*)d_in[1];
    const int*   dst    = (const int*)d_in[2];
    const float* W_in   = (const float*)d_in[3];
    const float* b_in   = (const float*)d_in[4];
    const float* W_edge = (const float*)d_in[5];
    const float* b_edge = (const float*)d_in[6];
    const float* W_out  = (const float*)d_in[7];
    const float* b_out  = (const float*)d_in[8];
    float* out = (float*)d_out;

    // workspace layout
    u16*   h16           = (u16*)d_ws;                           // N*F bf16
    float* A             = (float*)(h16 + (size_t)N_NODES * F);  // N
    float* B             = A + N_NODES;                          // N
    int*   row_ptr       = (int*)(B + N_NODES);                  // N+1
    int*   bucket_cnt    = row_ptr + N_NODES + 1;                // NB
    int*   bucket_base   = bucket_cnt + NB;                      // NB+1
    int*   bucket_cursor = bucket_base + NB + 1;                 // NB
    int*   src_sorted    = bucket_cursor + NB;                   // E
    int2*  pairs         = (int2*)(src_sorted + N_EDGES);        // E (8B each)

    hipMemsetAsync(bucket_cnt, 0, NB * sizeof(int), stream);

    const int blocks_mlp   = (N_NODES + TM - 1) / TM;
    const int blocks_nodes = (N_NODES + 3) / 4;

    node_mlp_kernel<<<blocks_mlp, 256, 0, stream>>>(feat, W_in, b_in, W_edge, h16, A, B);
    bin_count_kernel<<<256, 256, 0, stream>>>(dst, bucket_cnt);
    bucket_scan_kernel<<<1, 1024, 0, stream>>>(bucket_cnt, bucket_base, bucket_cursor, row_ptr);
    bin_scatter_kernel<<<256, 256, 0, stream>>>(src, dst, bucket_cursor, pairs);
    fine_sort_kernel<<<NB, 256, 0, stream>>>(pairs, bucket_base, row_ptr, src_sorted);
    agg_out_kernel<<<blocks_nodes, 256, 0, stream>>>(h16, A, B, b_edge, row_ptr, src_sorted,
                                                     W_out, b_out, out);
}